// Round 7
// baseline (407.591 us; speedup 1.0000x reference)
//
#include <hip/hip_runtime.h>
#include <math.h>

// AttnBlock: GroupNorm(32) -> q,k,v 1x1 -> spatial attention -> proj -> resid.
// Round 7: qkv rewritten as bf16 MFMA with fused GN-apply (gn_stats + prep_w
// + qkvg); attention = round-6 structure with register prefetch restored
// (round 6 regression: staging after the barrier exposed ~900 cyc/tile).

#define BB 4
#define CCH 256
#define NSP 4096
#define EPSV 1e-5f
#define ATTN_SCALE 0.0625f  // 256^-0.5
#define RSQRT2 0.70710678118654752440f
#define KSPLIT 4
#define TILES_PER_PART 16   // 4096 / 64 / KSPLIT

typedef __attribute__((ext_vector_type(8))) short bf16x8;
typedef __attribute__((ext_vector_type(4))) short bf16x4;
typedef __attribute__((ext_vector_type(4))) float f32x4;

__device__ __forceinline__ short f2bf(float f) {
  union { float f; unsigned u; } a; a.f = f;
  unsigned r = a.u + 0x7fffu + ((a.u >> 16) & 1u);  // RTN-even
  return (short)(r >> 16);
}
__device__ __forceinline__ float bf2f(short s) {
  union { unsigned u; float f; } a;
  a.u = ((unsigned)(unsigned short)s) << 16;
  return a.f;
}

__device__ __forceinline__ f32x4 mfma16x16x16(bf16x4 a, bf16x4 b, f32x4 c) {
#if __has_builtin(__builtin_amdgcn_mfma_f32_16x16x16bf16_1k)
  return __builtin_amdgcn_mfma_f32_16x16x16bf16_1k(a, b, c, 0, 0, 0);
#else
  asm volatile("v_mfma_f32_16x16x16_bf16 %0, %1, %2, %0"
               : "+v"(c) : "v"(a), "v"(b));
  return c;
#endif
}

// ---------------- GroupNorm stats only: mean/rstd per (b,g) ----------------
__global__ __launch_bounds__(256) void gn_stats(
    const float* __restrict__ x, float* __restrict__ stats) {
  int b = blockIdx.x >> 5;
  int g = blockIdx.x & 31;
  size_t base = ((size_t)b * CCH + (size_t)g * 8) * NSP;
  const float4* xv = (const float4*)(x + base);
  int tid = threadIdx.x;
  float s = 0.f, ss = 0.f;
  for (int i = tid; i < 8192; i += 256) {
    float4 v = xv[i];
    s += (v.x + v.y) + (v.z + v.w);
    ss += (v.x * v.x + v.y * v.y) + (v.z * v.z + v.w * v.w);
  }
#pragma unroll
  for (int off = 32; off > 0; off >>= 1) {
    s += __shfl_down(s, off, 64);
    ss += __shfl_down(ss, off, 64);
  }
  __shared__ float rs[4], rss[4];
  int wv = tid >> 6;
  if ((tid & 63) == 0) { rs[wv] = s; rss[wv] = ss; }
  __syncthreads();
  if (tid == 0) {
    float S = rs[0] + rs[1] + rs[2] + rs[3];
    float SS = rss[0] + rss[1] + rss[2] + rss[3];
    float mean = S * (1.f / 32768.f);
    float var = SS * (1.f / 32768.f) - mean * mean;
    stats[(b * 32 + g) * 2 + 0] = mean;
    stats[(b * 32 + g) * 2 + 1] = rsqrtf(var + EPSV);
  }
}

// ------------- prep: W [c][d] fp32 -> [d][c] bf16, 4 weights --------------
__global__ __launch_bounds__(256) void prep_w(
    const float* __restrict__ Wq, const float* __restrict__ Wk,
    const float* __restrict__ Wv, const float* __restrict__ Wp,
    short* __restrict__ wts) {
  __shared__ float T[64][65];
  int c0 = blockIdx.x * 64, d0 = blockIdx.y * 64;
  int wz = blockIdx.z;
  const float* W = (wz == 0) ? Wq : (wz == 1) ? Wk : (wz == 2) ? Wv : Wp;
  short* wt = wts + (size_t)wz * CCH * CCH;
  int tid = threadIdx.x;
#pragma unroll
  for (int i = 0; i < 16; ++i) {
    int idx = tid + 256 * i;
    int row = idx >> 6, col = idx & 63;
    T[row][col] = W[(size_t)(c0 + row) * CCH + d0 + col];
  }
  __syncthreads();
#pragma unroll
  for (int i = 0; i < 16; ++i) {
    int idx = tid + 256 * i;
    int dr = idx >> 6, cc = idx & 63;
    wt[(size_t)(d0 + dr) * CCH + c0 + cc] = f2bf(T[cc][dr]);
  }
}

// ------- qkvg: fused GN-apply + q,k,v projections via bf16 MFMA -----------
// Per block: (b, 64 spatial positions). Emits q,k [b][n][c] bf16 (q scaled),
// v [b][c][n] bf16.
__global__ __launch_bounds__(256) void qkvg_kernel(
    const float* __restrict__ x, const float* __restrict__ stats,
    const float* __restrict__ gw, const float* __restrict__ gb,
    const short* __restrict__ wqt, const short* __restrict__ wkt,
    const short* __restrict__ wvt,
    const float* __restrict__ bq, const float* __restrict__ bk,
    const float* __restrict__ bv,
    short* __restrict__ qo, short* __restrict__ ko, short* __restrict__ vo) {
  __shared__ __align__(16) unsigned char smem[52224];
  float (*Ts)[68] = (float(*)[68])smem;          // 64 x 68 fp32 (17408 B)
  float* aco = (float*)(smem + 17408);           // 256 f32
  float* bco = aco + 256;                        // 256 f32
  short* Hs = (short*)(smem + 19456);            // [64 n][256 c] swizzled bf16
  short* Fo = (short*)smem;                      // epilogue [64 n][264] bf16

  int bx = blockIdx.x;
  int b = bx & 3, n0 = (bx >> 2) * 64;
  int tid = threadIdx.x;
  {  // per-channel scale/shift
    int g = tid >> 3;
    float mean = stats[(b * 32 + g) * 2 + 0];
    float rstd = stats[(b * 32 + g) * 2 + 1];
    float a = gw[tid] * rstd;
    aco[tid] = a;
    bco[tid] = gb[tid] - mean * a;
  }
  __syncthreads();
  const float* xb = x + (size_t)b * CCH * NSP;
  // ---- 4 passes: load x chunk, normalize, transpose, bf16 -> swizzled Hs --
  for (int p = 0; p < 4; ++p) {
    int c0 = p * 64;
#pragma unroll
    for (int i = 0; i < 4; ++i) {
      int crow = (tid >> 4) + i * 16;
      int c = c0 + crow;
      float4 v = *(const float4*)&xb[(size_t)c * NSP + n0 + (tid & 15) * 4];
      float a = aco[c], bb = bco[c];
      v.x = v.x * a + bb; v.y = v.y * a + bb;
      v.z = v.z * a + bb; v.w = v.w * a + bb;
      *(float4*)&Ts[crow][(tid & 15) * 4] = v;   // Ts[c_local][n_local]
    }
    __syncthreads();
    {
      int n = tid >> 2, seg = tid & 3;
#pragma unroll
      for (int u = 0; u < 2; ++u) {
        int cb = seg * 16 + u * 8;
        bf16x8 r;
#pragma unroll
        for (int j = 0; j < 8; ++j) r[j] = f2bf(Ts[cb + j][n]);
        int chunk = (c0 + cb) >> 3;
        *(bf16x8*)(Hs + n * 256 + ((chunk ^ (n & 7)) * 8)) = r;
      }
    }
    __syncthreads();
  }
  // ---- extract B-frags (rows = this wave's 16 n) ----
  int w = tid >> 6, lane = tid & 63, quad = lane >> 4, l16 = lane & 15;
  bf16x8 a_h[8];
  {
    int row = w * 16 + l16;
#pragma unroll
    for (int kc = 0; kc < 8; ++kc)
      a_h[kc] = *(bf16x8*)(Hs + row * 256 + (((kc * 4 + quad) ^ (row & 7)) * 8));
  }
  __syncthreads();  // all waves extracted; smem reusable as Fo
  // ---- 3 projections ----
  for (int op = 0; op < 3; ++op) {
    const short* wt = (op == 0) ? wqt : (op == 1) ? wkt : wvt;
    const float* bias = (op == 0) ? bq : (op == 1) ? bk : bv;
    f32x4 acc[16];
#pragma unroll
    for (int mb = 0; mb < 16; ++mb) acc[mb] = (f32x4){0.f, 0.f, 0.f, 0.f};
#pragma unroll 4
    for (int mb = 0; mb < 16; ++mb) {
      const short* wp = wt + (size_t)(mb * 16 + l16) * CCH + quad * 8;
#pragma unroll
      for (int kc = 0; kc < 8; ++kc) {
        bf16x8 af = *(const bf16x8*)(wp + kc * 32);
        acc[mb] = __builtin_amdgcn_mfma_f32_16x16x32_bf16(af, a_h[kc], acc[mb], 0, 0, 0);
      }
    }
    int n = n0 + w * 16 + l16;
    if (op == 2) {  // v: [c][n] direct scalar stores (32B runs per quad-row)
      short* ob = vo + (size_t)b * CCH * NSP;
#pragma unroll
      for (int mb = 0; mb < 16; ++mb)
#pragma unroll
        for (int r = 0; r < 4; ++r) {
          int d = mb * 16 + quad * 4 + r;
          ob[(size_t)d * NSP + n] = f2bf(acc[mb][r] + bias[d]);
        }
    } else {  // q/k: transpose via Fo -> [n][c] b128 stores
      float sc = (op == 0) ? ATTN_SCALE : 1.f;
      int nl = w * 16 + l16;
#pragma unroll
      for (int mb = 0; mb < 16; ++mb)
#pragma unroll
        for (int r = 0; r < 4; ++r) {
          int d = mb * 16 + quad * 4 + r;
          Fo[nl * 264 + d] = f2bf((acc[mb][r] + bias[d]) * sc);
        }
      __syncthreads();
      short* ob = ((op == 0) ? qo : ko) + (size_t)b * NSP * CCH;
#pragma unroll
      for (int it = 0; it < 2; ++it) {
        int idx = tid + 256 * it;
        int row = idx >> 3, seg = idx & 7;
        short* dst = ob + (size_t)(n0 + row) * CCH + seg * 32;
#pragma unroll
        for (int i = 0; i < 4; ++i)
          *(bf16x8*)(dst + i * 8) = *(bf16x8*)(Fo + row * 264 + seg * 32 + i * 8);
      }
      __syncthreads();
    }
  }
}

// ---------------- flash attention: 8 waves, 32 q/wave, 256 q/block ---------
// q,k: [b][n][c] bf16 (q pre-scaled); v: [b][c][n] bf16.
// Writes NORMALIZED partial O^T [kh][b][n][c] bf16 + m,l stats [kh][b][n].
__global__ __launch_bounds__(512, 2) void attn_kernel(
    const short* __restrict__ q, const short* __restrict__ k,
    const short* __restrict__ v, short* __restrict__ po,
    float* __restrict__ pm, float* __restrict__ pl) {
  __shared__ __align__(16) unsigned char smem[65536];   // 64 KB
  short* Ks = (short*)smem;            // [64 m][256 c] swizzled (also Q stage)
  short* Vs = (short*)(smem + 32768);  // [256 c][64 m] swizzled
  short* Fo = (short*)smem;            // epilogue [64 n][264 c] bf16

  int bx = blockIdx.x;
  int b = bx & 3;
  int n0 = ((bx >> 2) & 15) << 8;   // 256-query block
  int kh = bx >> 6;                 // key quarter
  const short* qb = q + (size_t)b * NSP * CCH;
  const short* kb = k + (size_t)b * NSP * CCH;
  const short* vb = v + (size_t)b * CCH * NSP;
  int tid = threadIdx.x;
  int w = tid >> 6, lane = tid & 63, quad = lane >> 4, l16 = lane & 15;

  // staging geometry (512 threads)
  int krow = tid >> 3, kch8 = tid & 7;   // K/Q: row krow, chunks kch8+8i
  int ksw = (kch8 ^ (krow & 7)) * 8;     // swizzled base (chunk+8i keeps row&7)
  int vrow = tid >> 1, vc = tid & 1;     // V: row vrow, chunks vc*4+i

  // ---- stage Q in 4 passes of 64 rows through Ks; extract B-frags ----
  bf16x8 a_q[2][8];
#pragma unroll
  for (int p = 0; p < 4; ++p) {
    const short* qp = qb + (size_t)(n0 + p * 64 + krow) * CCH + kch8 * 8;
#pragma unroll
    for (int i = 0; i < 4; ++i)
      *(bf16x8*)(Ks + krow * 256 + ksw + 64 * i) = *(const bf16x8*)(qp + 64 * i);
    __syncthreads();
    if ((w >> 1) == p) {
#pragma unroll
      for (int nb = 0; nb < 2; ++nb) {
        int row = (w & 1) * 32 + nb * 16 + l16;
#pragma unroll
        for (int kc = 0; kc < 8; ++kc)
          a_q[nb][kc] =
              *(bf16x8*)(Ks + row * 256 + (((kc * 4 + quad) ^ (row & 7)) * 8));
      }
    }
    __syncthreads();
  }

  int mbase = kh * TILES_PER_PART * 64;
  // ---- stage tile 0 ----
  {
    const short* kp = kb + (size_t)(mbase + krow) * CCH + kch8 * 8;
#pragma unroll
    for (int i = 0; i < 4; ++i)
      *(bf16x8*)(Ks + krow * 256 + ksw + 64 * i) = *(const bf16x8*)(kp + 64 * i);
    const short* vp = vb + (size_t)vrow * NSP + mbase;
#pragma unroll
    for (int i = 0; i < 4; ++i) {
      int c = vc * 4 + i;
      *(bf16x8*)(Vs + vrow * 64 + ((c ^ (vrow & 7)) * 8)) =
          *(const bf16x8*)(vp + c * 8);
    }
  }
  __syncthreads();

  f32x4 accO[2][16];  // [nb][cb]: ch = cb*16+quad*4+r, query = w*32+nb*16+l16
#pragma unroll
  for (int nb = 0; nb < 2; ++nb)
#pragma unroll
    for (int cb = 0; cb < 16; ++cb) accO[nb][cb] = (f32x4){0.f, 0.f, 0.f, 0.f};
  float m_run[2] = {-1e30f, -1e30f}, l_run[2] = {0.f, 0.f};

#pragma unroll 1
  for (int t = 0; t < TILES_PER_PART; ++t) {
    // ---- prefetch next tile into registers (lands during compute) ----
    bf16x8 kr[4], vr[4];
    if (t < TILES_PER_PART - 1) {
      int m0 = mbase + (t + 1) * 64;
      const short* kp = kb + (size_t)(m0 + krow) * CCH + kch8 * 8;
#pragma unroll
      for (int i = 0; i < 4; ++i) kr[i] = *(const bf16x8*)(kp + 64 * i);
      const short* vp = vb + (size_t)vrow * NSP + m0;
#pragma unroll
      for (int i = 0; i < 4; ++i) vr[i] = *(const bf16x8*)(vp + (vc * 4 + i) * 8);
    }
    // ---- S^T = K Q^T : rows = 64 keys, cols = 2x16 queries ----
    f32x4 s[2][4];
#pragma unroll
    for (int nb = 0; nb < 2; ++nb)
#pragma unroll
      for (int mb = 0; mb < 4; ++mb) s[nb][mb] = (f32x4){0.f, 0.f, 0.f, 0.f};
#pragma unroll
    for (int kc = 0; kc < 8; ++kc) {
#pragma unroll
      for (int mb = 0; mb < 4; ++mb) {
        int row = mb * 16 + l16;
        bf16x8 kf = *(bf16x8*)(Ks + row * 256 + (((kc * 4 + quad) ^ (row & 7)) * 8));
        s[0][mb] = __builtin_amdgcn_mfma_f32_16x16x32_bf16(kf, a_q[0][kc], s[0][mb], 0, 0, 0);
        s[1][mb] = __builtin_amdgcn_mfma_f32_16x16x32_bf16(kf, a_q[1][kc], s[1][mb], 0, 0, 0);
      }
    }
    // ---- online softmax per nb (one query per lane) ----
    bf16x4 pb[2][4];
#pragma unroll
    for (int nb = 0; nb < 2; ++nb) {
      float mx = -1e30f;
#pragma unroll
      for (int mb = 0; mb < 4; ++mb)
#pragma unroll
        for (int r = 0; r < 4; ++r) mx = fmaxf(mx, s[nb][mb][r]);
      mx = fmaxf(mx, __shfl_xor(mx, 16));
      mx = fmaxf(mx, __shfl_xor(mx, 32));
      float mnew = fmaxf(m_run[nb], mx);
      float alpha = __expf(m_run[nb] - mnew);
      m_run[nb] = mnew;
      float ls = 0.f;
#pragma unroll
      for (int mb = 0; mb < 4; ++mb)
#pragma unroll
        for (int r = 0; r < 4; ++r) {
          float p = __expf(s[nb][mb][r] - mnew);
          ls += p;
          pb[nb][mb][r] = f2bf(p);
        }
      ls += __shfl_xor(ls, 16);
      ls += __shfl_xor(ls, 32);
      l_run[nb] = l_run[nb] * alpha + ls;
#pragma unroll
      for (int cb = 0; cb < 16; ++cb) accO[nb][cb] *= alpha;
    }
    // ---- O^T += V P^T : A = V-frag (b64), B = pb from registers ----
#pragma unroll
    for (int kw = 0; kw < 4; ++kw) {
#pragma unroll
      for (int cb = 0; cb < 16; ++cb) {
        int row = cb * 16 + l16;
        int chunk = (kw * 2 + (quad >> 1)) ^ (row & 7);
        bf16x4 vf = *(bf16x4*)(Vs + row * 64 + chunk * 8 + (quad & 1) * 4);
        accO[0][cb] = mfma16x16x16(vf, pb[0][kw], accO[0][cb]);
        accO[1][cb] = mfma16x16x16(vf, pb[1][kw], accO[1][cb]);
      }
    }
    __syncthreads();
    if (t < TILES_PER_PART - 1) {
#pragma unroll
      for (int i = 0; i < 4; ++i)
        *(bf16x8*)(Ks + krow * 256 + ksw + 64 * i) = kr[i];
#pragma unroll
      for (int i = 0; i < 4; ++i) {
        int c = vc * 4 + i;
        *(bf16x8*)(Vs + vrow * 64 + ((c ^ (vrow & 7)) * 8)) = vr[i];
      }
      __syncthreads();
    }
  }
  // ---- stats ----
  size_t sbase = ((size_t)kh * BB + b) * NSP + n0;
  if (quad == 0) {
#pragma unroll
    for (int nb = 0; nb < 2; ++nb) {
      pm[sbase + w * 32 + nb * 16 + l16] = m_run[nb];
      pl[sbase + w * 32 + nb * 16 + l16] = l_run[nb];
    }
  }
  // ---- epilogue: normalized bf16 O^T -> po [kh][b][n][c], LDS transpose ----
  float linv[2] = {1.f / l_run[0], 1.f / l_run[1]};
  short* ob = po + ((size_t)kh * BB + b) * NSP * CCH;
#pragma unroll
  for (int p = 0; p < 4; ++p) {
    __syncthreads();
    if ((w >> 1) == p) {
#pragma unroll
      for (int nb = 0; nb < 2; ++nb) {
        int nloc = (w & 1) * 32 + nb * 16 + l16;
#pragma unroll
        for (int cb = 0; cb < 16; ++cb)
#pragma unroll
          for (int r = 0; r < 4; ++r)
            Fo[nloc * 264 + cb * 16 + quad * 4 + r] = f2bf(accO[nb][cb][r] * linv[nb]);
      }
    }
    __syncthreads();
    int row = tid >> 3, seg = tid & 7;
    short* dst = ob + (size_t)(n0 + p * 64 + row) * CCH + seg * 32;
#pragma unroll
    for (int i = 0; i < 4; ++i)
      *(bf16x8*)(dst + i * 8) = *(bf16x8*)(Fo + row * 264 + seg * 32 + i * 8);
  }
}

// ------- proj: frag-direct MFMA, 4-way merge in registers, +bias+resid ------
__global__ __launch_bounds__(256) void proj_kernel(
    const short* __restrict__ po, const float* __restrict__ pm,
    const float* __restrict__ pl, const short* __restrict__ wpt,
    const float* __restrict__ bp, const float* __restrict__ x,
    float* __restrict__ out) {
  int n0 = blockIdx.x * 64;
  int dh = blockIdx.y * 128;
  int b = blockIdx.z;
  int tid = threadIdx.x;
  int w = tid >> 6, lane = tid & 63, quad = lane >> 4, l16 = lane & 15;
  int n = n0 + w * 16 + l16;

  float wgt[KSPLIT];
  {
    float m[KSPLIT], l[KSPLIT];
#pragma unroll
    for (int kh = 0; kh < KSPLIT; ++kh) {
      m[kh] = pm[((size_t)kh * BB + b) * NSP + n];
      l[kh] = pl[((size_t)kh * BB + b) * NSP + n];
    }
    float M = fmaxf(fmaxf(m[0], m[1]), fmaxf(m[2], m[3]));
    float L = 0.f;
#pragma unroll
    for (int kh = 0; kh < KSPLIT; ++kh) {
      wgt[kh] = __expf(m[kh] - M) * l[kh];
      L += wgt[kh];
    }
    float linv = 1.f / L;
#pragma unroll
    for (int kh = 0; kh < KSPLIT; ++kh) wgt[kh] *= linv;
  }

  f32x4 acc[8];
#pragma unroll
  for (int mb = 0; mb < 8; ++mb) acc[mb] = (f32x4){0.f, 0.f, 0.f, 0.f};

  const short* pob = po + ((size_t)b * NSP + n) * CCH;
#pragma unroll 2
  for (int kc = 0; kc < 8; ++kc) {
    int coff = kc * 32 + quad * 8;
    bf16x8 f0 = *(const bf16x8*)(pob + 0 * (size_t)BB * NSP * CCH + coff);
    bf16x8 f1 = *(const bf16x8*)(pob + 1 * (size_t)BB * NSP * CCH + coff);
    bf16x8 f2 = *(const bf16x8*)(pob + 2 * (size_t)BB * NSP * CCH + coff);
    bf16x8 f3 = *(const bf16x8*)(pob + 3 * (size_t)BB * NSP * CCH + coff);
    bf16x8 bm;
#pragma unroll
    for (int e = 0; e < 8; ++e) {
      float f = wgt[0] * bf2f(f0[e]) + wgt[1] * bf2f(f1[e]) +
                wgt[2] * bf2f(f2[e]) + wgt[3] * bf2f(f3[e]);
      bm[e] = f2bf(f);
    }
#pragma unroll
    for (int mb = 0; mb < 8; ++mb) {
      bf16x8 af = *(const bf16x8*)(wpt + (size_t)(dh + mb * 16 + l16) * CCH + coff);
      acc[mb] = __builtin_amdgcn_mfma_f32_16x16x32_bf16(af, bm, acc[mb], 0, 0, 0);
    }
  }
#pragma unroll
  for (int mb = 0; mb < 8; ++mb) {
#pragma unroll
    for (int r = 0; r < 4; ++r) {
      int d = dh + mb * 16 + quad * 4 + r;
      size_t off = ((size_t)b * CCH + d) * NSP + n;
      out[off] = (acc[mb][r] + bp[d] + x[off]) * RSQRT2;
    }
  }
}

extern "C" void kernel_launch(void* const* d_in, const int* in_sizes, int n_in,
                              void* d_out, int out_size, void* d_ws, size_t ws_size,
                              hipStream_t stream) {
  const float* x  = (const float*)d_in[0];
  const float* gw = (const float*)d_in[1];
  const float* gb = (const float*)d_in[2];
  const float* Wq = (const float*)d_in[3];
  const float* bq = (const float*)d_in[4];
  const float* Wk = (const float*)d_in[5];
  const float* bk = (const float*)d_in[6];
  const float* Wv = (const float*)d_in[7];
  const float* bv = (const float*)d_in[8];
  const float* Wp = (const float*)d_in[9];
  const float* bp = (const float*)d_in[10];
  float* out = (float*)d_out;

  const size_t SZ = (size_t)BB * CCH * NSP;  // 4.19M elems
  short* qb  = (short*)d_ws;                 // bf16 [b][n][c], pre-scaled
  short* kb  = qb + SZ;                      // bf16 [b][n][c]
  short* vb  = kb + SZ;                      // bf16 [b][c][n]
  short* poT = vb + SZ;                      // bf16 [4][b][n][c] normalized
  float* pm  = (float*)(poT + (size_t)KSPLIT * SZ);  // [4][b][n]
  float* pl  = pm + (size_t)KSPLIT * BB * NSP;
  float* stats = pl + (size_t)KSPLIT * BB * NSP;     // [b][32][2]
  short* wts = (short*)(stats + BB * 64);            // bf16 [4][256][256]
  short* wqt = wts;
  short* wkt = wts + (size_t)CCH * CCH;
  short* wvt = wts + (size_t)2 * CCH * CCH;
  short* wpt = wts + (size_t)3 * CCH * CCH;

  gn_stats<<<dim3(BB * 32), dim3(256), 0, stream>>>(x, stats);
  prep_w<<<dim3(4, 4, 4), dim3(256), 0, stream>>>(Wq, Wk, Wv, Wp, wts);
  qkvg_kernel<<<dim3(256), dim3(256), 0, stream>>>(
      x, stats, gw, gb, wqt, wkt, wvt, bq, bk, bv, qb, kb, vb);
  attn_kernel<<<dim3(256), dim3(512), 0, stream>>>(qb, kb, vb, poT, pm, pl);
  proj_kernel<<<dim3(64, 2, BB), dim3(256), 0, stream>>>(
      poT, pm, pl, wpt, bp, x, out);
}

// Round 8
// 407.272 us; speedup vs baseline: 1.0008x; 1.0008x over previous
//
#include <hip/hip_runtime.h>
#include <math.h>

// AttnBlock: GroupNorm(32) -> q,k,v 1x1 -> spatial attention -> proj -> resid.
// Round 8: round-7 pipeline with ONE fix: attn __launch_bounds__(512,1).
// (512,2) capped VGPRs at 128 while the kernel needs ~224 (accO[2][16]=128 +
// a_q[2][8]=64 + prefetch 32) -> massive scratch spills (FETCH 180MB / WRITE
// 305MB, round 7). (512,1) caps at 256; the 8-wave block still provides
// 2 waves/SIMD co-residency by itself.

#define BB 4
#define CCH 256
#define NSP 4096
#define EPSV 1e-5f
#define ATTN_SCALE 0.0625f  // 256^-0.5
#define RSQRT2 0.70710678118654752440f
#define KSPLIT 4
#define TILES_PER_PART 16   // 4096 / 64 / KSPLIT

typedef __attribute__((ext_vector_type(8))) short bf16x8;
typedef __attribute__((ext_vector_type(4))) short bf16x4;
typedef __attribute__((ext_vector_type(4))) float f32x4;

__device__ __forceinline__ short f2bf(float f) {
  union { float f; unsigned u; } a; a.f = f;
  unsigned r = a.u + 0x7fffu + ((a.u >> 16) & 1u);  // RTN-even
  return (short)(r >> 16);
}
__device__ __forceinline__ float bf2f(short s) {
  union { unsigned u; float f; } a;
  a.u = ((unsigned)(unsigned short)s) << 16;
  return a.f;
}

__device__ __forceinline__ f32x4 mfma16x16x16(bf16x4 a, bf16x4 b, f32x4 c) {
#if __has_builtin(__builtin_amdgcn_mfma_f32_16x16x16bf16_1k)
  return __builtin_amdgcn_mfma_f32_16x16x16bf16_1k(a, b, c, 0, 0, 0);
#else
  asm volatile("v_mfma_f32_16x16x16_bf16 %0, %1, %2, %0"
               : "+v"(c) : "v"(a), "v"(b));
  return c;
#endif
}

// ---------------- GroupNorm stats only: mean/rstd per (b,g) ----------------
__global__ __launch_bounds__(256) void gn_stats(
    const float* __restrict__ x, float* __restrict__ stats) {
  int b = blockIdx.x >> 5;
  int g = blockIdx.x & 31;
  size_t base = ((size_t)b * CCH + (size_t)g * 8) * NSP;
  const float4* xv = (const float4*)(x + base);
  int tid = threadIdx.x;
  float s = 0.f, ss = 0.f;
  for (int i = tid; i < 8192; i += 256) {
    float4 v = xv[i];
    s += (v.x + v.y) + (v.z + v.w);
    ss += (v.x * v.x + v.y * v.y) + (v.z * v.z + v.w * v.w);
  }
#pragma unroll
  for (int off = 32; off > 0; off >>= 1) {
    s += __shfl_down(s, off, 64);
    ss += __shfl_down(ss, off, 64);
  }
  __shared__ float rs[4], rss[4];
  int wv = tid >> 6;
  if ((tid & 63) == 0) { rs[wv] = s; rss[wv] = ss; }
  __syncthreads();
  if (tid == 0) {
    float S = rs[0] + rs[1] + rs[2] + rs[3];
    float SS = rss[0] + rss[1] + rss[2] + rss[3];
    float mean = S * (1.f / 32768.f);
    float var = SS * (1.f / 32768.f) - mean * mean;
    stats[(b * 32 + g) * 2 + 0] = mean;
    stats[(b * 32 + g) * 2 + 1] = rsqrtf(var + EPSV);
  }
}

// ------------- prep: W [c][d] fp32 -> [d][c] bf16, 4 weights --------------
__global__ __launch_bounds__(256) void prep_w(
    const float* __restrict__ Wq, const float* __restrict__ Wk,
    const float* __restrict__ Wv, const float* __restrict__ Wp,
    short* __restrict__ wts) {
  __shared__ float T[64][65];
  int c0 = blockIdx.x * 64, d0 = blockIdx.y * 64;
  int wz = blockIdx.z;
  const float* W = (wz == 0) ? Wq : (wz == 1) ? Wk : (wz == 2) ? Wv : Wp;
  short* wt = wts + (size_t)wz * CCH * CCH;
  int tid = threadIdx.x;
#pragma unroll
  for (int i = 0; i < 16; ++i) {
    int idx = tid + 256 * i;
    int row = idx >> 6, col = idx & 63;
    T[row][col] = W[(size_t)(c0 + row) * CCH + d0 + col];
  }
  __syncthreads();
#pragma unroll
  for (int i = 0; i < 16; ++i) {
    int idx = tid + 256 * i;
    int dr = idx >> 6, cc = idx & 63;
    wt[(size_t)(d0 + dr) * CCH + c0 + cc] = f2bf(T[cc][dr]);
  }
}

// ------- qkvg: fused GN-apply + q,k,v projections via bf16 MFMA -----------
__global__ __launch_bounds__(256) void qkvg_kernel(
    const float* __restrict__ x, const float* __restrict__ stats,
    const float* __restrict__ gw, const float* __restrict__ gb,
    const short* __restrict__ wqt, const short* __restrict__ wkt,
    const short* __restrict__ wvt,
    const float* __restrict__ bq, const float* __restrict__ bk,
    const float* __restrict__ bv,
    short* __restrict__ qo, short* __restrict__ ko, short* __restrict__ vo) {
  __shared__ __align__(16) unsigned char smem[52224];
  float (*Ts)[68] = (float(*)[68])smem;          // 64 x 68 fp32 (17408 B)
  float* aco = (float*)(smem + 17408);           // 256 f32
  float* bco = aco + 256;                        // 256 f32
  short* Hs = (short*)(smem + 19456);            // [64 n][256 c] swizzled bf16
  short* Fo = (short*)smem;                      // epilogue [64 n][264] bf16

  int bx = blockIdx.x;
  int b = bx & 3, n0 = (bx >> 2) * 64;
  int tid = threadIdx.x;
  {  // per-channel scale/shift
    int g = tid >> 3;
    float mean = stats[(b * 32 + g) * 2 + 0];
    float rstd = stats[(b * 32 + g) * 2 + 1];
    float a = gw[tid] * rstd;
    aco[tid] = a;
    bco[tid] = gb[tid] - mean * a;
  }
  __syncthreads();
  const float* xb = x + (size_t)b * CCH * NSP;
  // ---- 4 passes: load x chunk, normalize, transpose, bf16 -> swizzled Hs --
  for (int p = 0; p < 4; ++p) {
    int c0 = p * 64;
#pragma unroll
    for (int i = 0; i < 4; ++i) {
      int crow = (tid >> 4) + i * 16;
      int c = c0 + crow;
      float4 v = *(const float4*)&xb[(size_t)c * NSP + n0 + (tid & 15) * 4];
      float a = aco[c], bb = bco[c];
      v.x = v.x * a + bb; v.y = v.y * a + bb;
      v.z = v.z * a + bb; v.w = v.w * a + bb;
      *(float4*)&Ts[crow][(tid & 15) * 4] = v;   // Ts[c_local][n_local]
    }
    __syncthreads();
    {
      int n = tid >> 2, seg = tid & 3;
#pragma unroll
      for (int u = 0; u < 2; ++u) {
        int cb = seg * 16 + u * 8;
        bf16x8 r;
#pragma unroll
        for (int j = 0; j < 8; ++j) r[j] = f2bf(Ts[cb + j][n]);
        int chunk = (c0 + cb) >> 3;
        *(bf16x8*)(Hs + n * 256 + ((chunk ^ (n & 7)) * 8)) = r;
      }
    }
    __syncthreads();
  }
  // ---- extract B-frags (rows = this wave's 16 n) ----
  int w = tid >> 6, lane = tid & 63, quad = lane >> 4, l16 = lane & 15;
  bf16x8 a_h[8];
  {
    int row = w * 16 + l16;
#pragma unroll
    for (int kc = 0; kc < 8; ++kc)
      a_h[kc] = *(bf16x8*)(Hs + row * 256 + (((kc * 4 + quad) ^ (row & 7)) * 8));
  }
  __syncthreads();  // all waves extracted; smem reusable as Fo
  // ---- 3 projections ----
  for (int op = 0; op < 3; ++op) {
    const short* wt = (op == 0) ? wqt : (op == 1) ? wkt : wvt;
    const float* bias = (op == 0) ? bq : (op == 1) ? bk : bv;
    f32x4 acc[16];
#pragma unroll
    for (int mb = 0; mb < 16; ++mb) acc[mb] = (f32x4){0.f, 0.f, 0.f, 0.f};
#pragma unroll 4
    for (int mb = 0; mb < 16; ++mb) {
      const short* wp = wt + (size_t)(mb * 16 + l16) * CCH + quad * 8;
#pragma unroll
      for (int kc = 0; kc < 8; ++kc) {
        bf16x8 af = *(const bf16x8*)(wp + kc * 32);
        acc[mb] = __builtin_amdgcn_mfma_f32_16x16x32_bf16(af, a_h[kc], acc[mb], 0, 0, 0);
      }
    }
    int n = n0 + w * 16 + l16;
    if (op == 2) {  // v: [c][n] direct scalar stores
      short* ob = vo + (size_t)b * CCH * NSP;
#pragma unroll
      for (int mb = 0; mb < 16; ++mb)
#pragma unroll
        for (int r = 0; r < 4; ++r) {
          int d = mb * 16 + quad * 4 + r;
          ob[(size_t)d * NSP + n] = f2bf(acc[mb][r] + bias[d]);
        }
    } else {  // q/k: transpose via Fo -> [n][c] b128 stores
      float sc = (op == 0) ? ATTN_SCALE : 1.f;
      int nl = w * 16 + l16;
#pragma unroll
      for (int mb = 0; mb < 16; ++mb)
#pragma unroll
        for (int r = 0; r < 4; ++r) {
          int d = mb * 16 + quad * 4 + r;
          Fo[nl * 264 + d] = f2bf((acc[mb][r] + bias[d]) * sc);
        }
      __syncthreads();
      short* ob = ((op == 0) ? qo : ko) + (size_t)b * NSP * CCH;
#pragma unroll
      for (int it = 0; it < 2; ++it) {
        int idx = tid + 256 * it;
        int row = idx >> 3, seg = idx & 7;
        short* dst = ob + (size_t)(n0 + row) * CCH + seg * 32;
#pragma unroll
        for (int i = 0; i < 4; ++i)
          *(bf16x8*)(dst + i * 8) = *(bf16x8*)(Fo + row * 264 + seg * 32 + i * 8);
      }
      __syncthreads();
    }
  }
}

// ---------------- flash attention: 8 waves, 32 q/wave, 256 q/block ---------
// q,k: [b][n][c] bf16 (q pre-scaled); v: [b][c][n] bf16.
// Writes NORMALIZED partial O^T [kh][b][n][c] bf16 + m,l stats [kh][b][n].
// (512,1): 256-VGPR cap -- needs ~224 live regs, (512,2)'s 128 cap spilled.
__global__ __launch_bounds__(512, 1) void attn_kernel(
    const short* __restrict__ q, const short* __restrict__ k,
    const short* __restrict__ v, short* __restrict__ po,
    float* __restrict__ pm, float* __restrict__ pl) {
  __shared__ __align__(16) unsigned char smem[65536];   // 64 KB
  short* Ks = (short*)smem;            // [64 m][256 c] swizzled (also Q stage)
  short* Vs = (short*)(smem + 32768);  // [256 c][64 m] swizzled
  short* Fo = (short*)smem;            // epilogue [64 n][264 c] bf16

  int bx = blockIdx.x;
  int b = bx & 3;
  int n0 = ((bx >> 2) & 15) << 8;   // 256-query block
  int kh = bx >> 6;                 // key quarter
  const short* qb = q + (size_t)b * NSP * CCH;
  const short* kb = k + (size_t)b * NSP * CCH;
  const short* vb = v + (size_t)b * CCH * NSP;
  int tid = threadIdx.x;
  int w = tid >> 6, lane = tid & 63, quad = lane >> 4, l16 = lane & 15;

  // staging geometry (512 threads)
  int krow = tid >> 3, kch8 = tid & 7;   // K/Q: row krow, chunks kch8+8i
  int ksw = (kch8 ^ (krow & 7)) * 8;     // swizzled base (chunk+8i keeps row&7)
  int vrow = tid >> 1, vc = tid & 1;     // V: row vrow, chunks vc*4+i

  // ---- stage Q in 4 passes of 64 rows through Ks; extract B-frags ----
  bf16x8 a_q[2][8];
#pragma unroll
  for (int p = 0; p < 4; ++p) {
    const short* qp = qb + (size_t)(n0 + p * 64 + krow) * CCH + kch8 * 8;
#pragma unroll
    for (int i = 0; i < 4; ++i)
      *(bf16x8*)(Ks + krow * 256 + ksw + 64 * i) = *(const bf16x8*)(qp + 64 * i);
    __syncthreads();
    if ((w >> 1) == p) {
#pragma unroll
      for (int nb = 0; nb < 2; ++nb) {
        int row = (w & 1) * 32 + nb * 16 + l16;
#pragma unroll
        for (int kc = 0; kc < 8; ++kc)
          a_q[nb][kc] =
              *(bf16x8*)(Ks + row * 256 + (((kc * 4 + quad) ^ (row & 7)) * 8));
      }
    }
    __syncthreads();
  }

  int mbase = kh * TILES_PER_PART * 64;
  // ---- stage tile 0 ----
  {
    const short* kp = kb + (size_t)(mbase + krow) * CCH + kch8 * 8;
#pragma unroll
    for (int i = 0; i < 4; ++i)
      *(bf16x8*)(Ks + krow * 256 + ksw + 64 * i) = *(const bf16x8*)(kp + 64 * i);
    const short* vp = vb + (size_t)vrow * NSP + mbase;
#pragma unroll
    for (int i = 0; i < 4; ++i) {
      int c = vc * 4 + i;
      *(bf16x8*)(Vs + vrow * 64 + ((c ^ (vrow & 7)) * 8)) =
          *(const bf16x8*)(vp + c * 8);
    }
  }
  __syncthreads();

  f32x4 accO[2][16];  // [nb][cb]: ch = cb*16+quad*4+r, query = w*32+nb*16+l16
#pragma unroll
  for (int nb = 0; nb < 2; ++nb)
#pragma unroll
    for (int cb = 0; cb < 16; ++cb) accO[nb][cb] = (f32x4){0.f, 0.f, 0.f, 0.f};
  float m_run[2] = {-1e30f, -1e30f}, l_run[2] = {0.f, 0.f};

#pragma unroll 1
  for (int t = 0; t < TILES_PER_PART; ++t) {
    // ---- prefetch next tile into registers (lands during compute) ----
    bf16x8 kr[4], vr[4];
    if (t < TILES_PER_PART - 1) {
      int m0 = mbase + (t + 1) * 64;
      const short* kp = kb + (size_t)(m0 + krow) * CCH + kch8 * 8;
#pragma unroll
      for (int i = 0; i < 4; ++i) kr[i] = *(const bf16x8*)(kp + 64 * i);
      const short* vp = vb + (size_t)vrow * NSP + m0;
#pragma unroll
      for (int i = 0; i < 4; ++i) vr[i] = *(const bf16x8*)(vp + (vc * 4 + i) * 8);
    }
    // ---- S^T = K Q^T : rows = 64 keys, cols = 2x16 queries ----
    f32x4 s[2][4];
#pragma unroll
    for (int nb = 0; nb < 2; ++nb)
#pragma unroll
      for (int mb = 0; mb < 4; ++mb) s[nb][mb] = (f32x4){0.f, 0.f, 0.f, 0.f};
#pragma unroll
    for (int kc = 0; kc < 8; ++kc) {
#pragma unroll
      for (int mb = 0; mb < 4; ++mb) {
        int row = mb * 16 + l16;
        bf16x8 kf = *(bf16x8*)(Ks + row * 256 + (((kc * 4 + quad) ^ (row & 7)) * 8));
        s[0][mb] = __builtin_amdgcn_mfma_f32_16x16x32_bf16(kf, a_q[0][kc], s[0][mb], 0, 0, 0);
        s[1][mb] = __builtin_amdgcn_mfma_f32_16x16x32_bf16(kf, a_q[1][kc], s[1][mb], 0, 0, 0);
      }
    }
    // ---- online softmax per nb (one query per lane) ----
    bf16x4 pb[2][4];
#pragma unroll
    for (int nb = 0; nb < 2; ++nb) {
      float mx = -1e30f;
#pragma unroll
      for (int mb = 0; mb < 4; ++mb)
#pragma unroll
        for (int r = 0; r < 4; ++r) mx = fmaxf(mx, s[nb][mb][r]);
      mx = fmaxf(mx, __shfl_xor(mx, 16));
      mx = fmaxf(mx, __shfl_xor(mx, 32));
      float mnew = fmaxf(m_run[nb], mx);
      float alpha = __expf(m_run[nb] - mnew);
      m_run[nb] = mnew;
      float ls = 0.f;
#pragma unroll
      for (int mb = 0; mb < 4; ++mb)
#pragma unroll
        for (int r = 0; r < 4; ++r) {
          float p = __expf(s[nb][mb][r] - mnew);
          ls += p;
          pb[nb][mb][r] = f2bf(p);
        }
      ls += __shfl_xor(ls, 16);
      ls += __shfl_xor(ls, 32);
      l_run[nb] = l_run[nb] * alpha + ls;
#pragma unroll
      for (int cb = 0; cb < 16; ++cb) accO[nb][cb] *= alpha;
    }
    // ---- O^T += V P^T : A = V-frag (b64), B = pb from registers ----
#pragma unroll
    for (int kw = 0; kw < 4; ++kw) {
#pragma unroll
      for (int cb = 0; cb < 16; ++cb) {
        int row = cb * 16 + l16;
        int chunk = (kw * 2 + (quad >> 1)) ^ (row & 7);
        bf16x4 vf = *(bf16x4*)(Vs + row * 64 + chunk * 8 + (quad & 1) * 4);
        accO[0][cb] = mfma16x16x16(vf, pb[0][kw], accO[0][cb]);
        accO[1][cb] = mfma16x16x16(vf, pb[1][kw], accO[1][cb]);
      }
    }
    __syncthreads();
    if (t < TILES_PER_PART - 1) {
#pragma unroll
      for (int i = 0; i < 4; ++i)
        *(bf16x8*)(Ks + krow * 256 + ksw + 64 * i) = kr[i];
#pragma unroll
      for (int i = 0; i < 4; ++i) {
        int c = vc * 4 + i;
        *(bf16x8*)(Vs + vrow * 64 + ((c ^ (vrow & 7)) * 8)) = vr[i];
      }
      __syncthreads();
    }
  }
  // ---- stats ----
  size_t sbase = ((size_t)kh * BB + b) * NSP + n0;
  if (quad == 0) {
#pragma unroll
    for (int nb = 0; nb < 2; ++nb) {
      pm[sbase + w * 32 + nb * 16 + l16] = m_run[nb];
      pl[sbase + w * 32 + nb * 16 + l16] = l_run[nb];
    }
  }
  // ---- epilogue: normalized bf16 O^T -> po [kh][b][n][c], LDS transpose ----
  float linv[2] = {1.f / l_run[0], 1.f / l_run[1]};
  short* ob = po + ((size_t)kh * BB + b) * NSP * CCH;
#pragma unroll
  for (int p = 0; p < 4; ++p) {
    __syncthreads();
    if ((w >> 1) == p) {
#pragma unroll
      for (int nb = 0; nb < 2; ++nb) {
        int nloc = (w & 1) * 32 + nb * 16 + l16;
#pragma unroll
        for (int cb = 0; cb < 16; ++cb)
#pragma unroll
          for (int r = 0; r < 4; ++r)
            Fo[nloc * 264 + cb * 16 + quad * 4 + r] = f2bf(accO[nb][cb][r] * linv[nb]);
      }
    }
    __syncthreads();
    int row = tid >> 3, seg = tid & 7;
    short* dst = ob + (size_t)(n0 + p * 64 + row) * CCH + seg * 32;
#pragma unroll
    for (int i = 0; i < 4; ++i)
      *(bf16x8*)(dst + i * 8) = *(bf16x8*)(Fo + row * 264 + seg * 32 + i * 8);
  }
}

// ------- proj: frag-direct MFMA, 4-way merge in registers, +bias+resid ------
__global__ __launch_bounds__(256) void proj_kernel(
    const short* __restrict__ po, const float* __restrict__ pm,
    const float* __restrict__ pl, const short* __restrict__ wpt,
    const float* __restrict__ bp, const float* __restrict__ x,
    float* __restrict__ out) {
  int n0 = blockIdx.x * 64;
  int dh = blockIdx.y * 128;
  int b = blockIdx.z;
  int tid = threadIdx.x;
  int w = tid >> 6, lane = tid & 63, quad = lane >> 4, l16 = lane & 15;
  int n = n0 + w * 16 + l16;

  float wgt[KSPLIT];
  {
    float m[KSPLIT], l[KSPLIT];
#pragma unroll
    for (int kh = 0; kh < KSPLIT; ++kh) {
      m[kh] = pm[((size_t)kh * BB + b) * NSP + n];
      l[kh] = pl[((size_t)kh * BB + b) * NSP + n];
    }
    float M = fmaxf(fmaxf(m[0], m[1]), fmaxf(m[2], m[3]));
    float L = 0.f;
#pragma unroll
    for (int kh = 0; kh < KSPLIT; ++kh) {
      wgt[kh] = __expf(m[kh] - M) * l[kh];
      L += wgt[kh];
    }
    float linv = 1.f / L;
#pragma unroll
    for (int kh = 0; kh < KSPLIT; ++kh) wgt[kh] *= linv;
  }

  f32x4 acc[8];
#pragma unroll
  for (int mb = 0; mb < 8; ++mb) acc[mb] = (f32x4){0.f, 0.f, 0.f, 0.f};

  const short* pob = po + ((size_t)b * NSP + n) * CCH;
#pragma unroll 2
  for (int kc = 0; kc < 8; ++kc) {
    int coff = kc * 32 + quad * 8;
    bf16x8 f0 = *(const bf16x8*)(pob + 0 * (size_t)BB * NSP * CCH + coff);
    bf16x8 f1 = *(const bf16x8*)(pob + 1 * (size_t)BB * NSP * CCH + coff);
    bf16x8 f2 = *(const bf16x8*)(pob + 2 * (size_t)BB * NSP * CCH + coff);
    bf16x8 f3 = *(const bf16x8*)(pob + 3 * (size_t)BB * NSP * CCH + coff);
    bf16x8 bm;
#pragma unroll
    for (int e = 0; e < 8; ++e) {
      float f = wgt[0] * bf2f(f0[e]) + wgt[1] * bf2f(f1[e]) +
                wgt[2] * bf2f(f2[e]) + wgt[3] * bf2f(f3[e]);
      bm[e] = f2bf(f);
    }
#pragma unroll
    for (int mb = 0; mb < 8; ++mb) {
      bf16x8 af = *(const bf16x8*)(wpt + (size_t)(dh + mb * 16 + l16) * CCH + coff);
      acc[mb] = __builtin_amdgcn_mfma_f32_16x16x32_bf16(af, bm, acc[mb], 0, 0, 0);
    }
  }
#pragma unroll
  for (int mb = 0; mb < 8; ++mb) {
#pragma unroll
    for (int r = 0; r < 4; ++r) {
      int d = dh + mb * 16 + quad * 4 + r;
      size_t off = ((size_t)b * CCH + d) * NSP + n;
      out[off] = (acc[mb][r] + bp[d] + x[off]) * RSQRT2;
    }
  }
}

extern "C" void kernel_launch(void* const* d_in, const int* in_sizes, int n_in,
                              void* d_out, int out_size, void* d_ws, size_t ws_size,
                              hipStream_t stream) {
  const float* x  = (const float*)d_in[0];
  const float* gw = (const float*)d_in[1];
  const float* gb = (const float*)d_in[2];
  const float* Wq = (const float*)d_in[3];
  const float* bq = (const float*)d_in[4];
  const float* Wk = (const float*)d_in[5];
  const float* bk = (const float*)d_in[6];
  const float* Wv = (const float*)d_in[7];
  const float* bv = (const float*)d_in[8];
  const float* Wp = (const float*)d_in[9];
  const float* bp = (const float*)d_in[10];
  float* out = (float*)d_out;

  const size_t SZ = (size_t)BB * CCH * NSP;  // 4.19M elems
  short* qb  = (short*)d_ws;                 // bf16 [b][n][c], pre-scaled
  short* kb  = qb + SZ;                      // bf16 [b][n][c]
  short* vb  = kb + SZ;                      // bf16 [b][c][n]
  short* poT = vb + SZ;                      // bf16 [4][b][n][c] normalized
  float* pm  = (float*)(poT + (size_t)KSPLIT * SZ);  // [4][b][n]
  float* pl  = pm + (size_t)KSPLIT * BB * NSP;
  float* stats = pl + (size_t)KSPLIT * BB * NSP;     // [b][32][2]
  short* wts = (short*)(stats + BB * 64);            // bf16 [4][256][256]
  short* wqt = wts;
  short* wkt = wts + (size_t)CCH * CCH;
  short* wvt = wts + (size_t)2 * CCH * CCH;
  short* wpt = wts + (size_t)3 * CCH * CCH;

  gn_stats<<<dim3(BB * 32), dim3(256), 0, stream>>>(x, stats);
  prep_w<<<dim3(4, 4, 4), dim3(256), 0, stream>>>(Wq, Wk, Wv, Wp, wts);
  qkvg_kernel<<<dim3(256), dim3(256), 0, stream>>>(
      x, stats, gw, gb, wqt, wkt, wvt, bq, bk, bv, qb, kb, vb);
  attn_kernel<<<dim3(256), dim3(512), 0, stream>>>(qb, kb, vb, poT, pm, pl);
  proj_kernel<<<dim3(64, 2, BB), dim3(256), 0, stream>>>(
      poT, pm, pl, wpt, bp, x, out);
}

// Round 9
// 318.994 us; speedup vs baseline: 1.2777x; 1.2767x over previous
//
#include <hip/hip_runtime.h>
#include <math.h>

// AttnBlock: GroupNorm(32) -> q,k,v 1x1 -> spatial attention -> proj -> resid.
// Round 9: attn reverted to the round-5 register shape (16 q/wave, accO[16],
// no spills -- rounds 6-8's 32 q/wave needs ~160 arch VGPRs vs the 128 cap at
// 2 waves/SIMD and always spilled). Keeps round 7's MFMA qkvg/prep/proj, with
// KSPLIT=2 and normalized bf16 attn output in [n][c] feeding frag-direct proj.

#define BB 4
#define CCH 256
#define NSP 4096
#define EPSV 1e-5f
#define ATTN_SCALE 0.0625f  // 256^-0.5
#define RSQRT2 0.70710678118654752440f
#define KSPLIT 2
#define TILES_PER_PART 32   // 4096 / 64 / KSPLIT

typedef __attribute__((ext_vector_type(8))) short bf16x8;
typedef __attribute__((ext_vector_type(4))) short bf16x4;
typedef __attribute__((ext_vector_type(4))) float f32x4;

__device__ __forceinline__ short f2bf(float f) {
  union { float f; unsigned u; } a; a.f = f;
  unsigned r = a.u + 0x7fffu + ((a.u >> 16) & 1u);  // RTN-even
  return (short)(r >> 16);
}
__device__ __forceinline__ float bf2f(short s) {
  union { unsigned u; float f; } a;
  a.u = ((unsigned)(unsigned short)s) << 16;
  return a.f;
}

__device__ __forceinline__ f32x4 mfma16x16x16(bf16x4 a, bf16x4 b, f32x4 c) {
#if __has_builtin(__builtin_amdgcn_mfma_f32_16x16x16bf16_1k)
  return __builtin_amdgcn_mfma_f32_16x16x16bf16_1k(a, b, c, 0, 0, 0);
#else
  asm volatile("v_mfma_f32_16x16x16_bf16 %0, %1, %2, %0"
               : "+v"(c) : "v"(a), "v"(b));
  return c;
#endif
}

// ---------------- GroupNorm stats only: mean/rstd per (b,g) ----------------
__global__ __launch_bounds__(256) void gn_stats(
    const float* __restrict__ x, float* __restrict__ stats) {
  int b = blockIdx.x >> 5;
  int g = blockIdx.x & 31;
  size_t base = ((size_t)b * CCH + (size_t)g * 8) * NSP;
  const float4* xv = (const float4*)(x + base);
  int tid = threadIdx.x;
  float s = 0.f, ss = 0.f;
  for (int i = tid; i < 8192; i += 256) {
    float4 v = xv[i];
    s += (v.x + v.y) + (v.z + v.w);
    ss += (v.x * v.x + v.y * v.y) + (v.z * v.z + v.w * v.w);
  }
#pragma unroll
  for (int off = 32; off > 0; off >>= 1) {
    s += __shfl_down(s, off, 64);
    ss += __shfl_down(ss, off, 64);
  }
  __shared__ float rs[4], rss[4];
  int wv = tid >> 6;
  if ((tid & 63) == 0) { rs[wv] = s; rss[wv] = ss; }
  __syncthreads();
  if (tid == 0) {
    float S = rs[0] + rs[1] + rs[2] + rs[3];
    float SS = rss[0] + rss[1] + rss[2] + rss[3];
    float mean = S * (1.f / 32768.f);
    float var = SS * (1.f / 32768.f) - mean * mean;
    stats[(b * 32 + g) * 2 + 0] = mean;
    stats[(b * 32 + g) * 2 + 1] = rsqrtf(var + EPSV);
  }
}

// ------------- prep: W [c][d] fp32 -> [d][c] bf16, 4 weights --------------
__global__ __launch_bounds__(256) void prep_w(
    const float* __restrict__ Wq, const float* __restrict__ Wk,
    const float* __restrict__ Wv, const float* __restrict__ Wp,
    short* __restrict__ wts) {
  __shared__ float T[64][65];
  int c0 = blockIdx.x * 64, d0 = blockIdx.y * 64;
  int wz = blockIdx.z;
  const float* W = (wz == 0) ? Wq : (wz == 1) ? Wk : (wz == 2) ? Wv : Wp;
  short* wt = wts + (size_t)wz * CCH * CCH;
  int tid = threadIdx.x;
#pragma unroll
  for (int i = 0; i < 16; ++i) {
    int idx = tid + 256 * i;
    int row = idx >> 6, col = idx & 63;
    T[row][col] = W[(size_t)(c0 + row) * CCH + d0 + col];
  }
  __syncthreads();
#pragma unroll
  for (int i = 0; i < 16; ++i) {
    int idx = tid + 256 * i;
    int dr = idx >> 6, cc = idx & 63;
    wt[(size_t)(d0 + dr) * CCH + c0 + cc] = f2bf(T[cc][dr]);
  }
}

// ------- qkvg: fused GN-apply + q,k,v projections via bf16 MFMA -----------
__global__ __launch_bounds__(256) void qkvg_kernel(
    const float* __restrict__ x, const float* __restrict__ stats,
    const float* __restrict__ gw, const float* __restrict__ gb,
    const short* __restrict__ wqt, const short* __restrict__ wkt,
    const short* __restrict__ wvt,
    const float* __restrict__ bq, const float* __restrict__ bk,
    const float* __restrict__ bv,
    short* __restrict__ qo, short* __restrict__ ko, short* __restrict__ vo) {
  __shared__ __align__(16) unsigned char smem[52224];
  float (*Ts)[68] = (float(*)[68])smem;          // 64 x 68 fp32 (17408 B)
  float* aco = (float*)(smem + 17408);           // 256 f32
  float* bco = aco + 256;                        // 256 f32
  short* Hs = (short*)(smem + 19456);            // [64 n][256 c] swizzled bf16
  short* Fo = (short*)smem;                      // epilogue [64 n][264] bf16

  int bx = blockIdx.x;
  int b = bx & 3, n0 = (bx >> 2) * 64;
  int tid = threadIdx.x;
  {  // per-channel scale/shift
    int g = tid >> 3;
    float mean = stats[(b * 32 + g) * 2 + 0];
    float rstd = stats[(b * 32 + g) * 2 + 1];
    float a = gw[tid] * rstd;
    aco[tid] = a;
    bco[tid] = gb[tid] - mean * a;
  }
  __syncthreads();
  const float* xb = x + (size_t)b * CCH * NSP;
  // ---- 4 passes: load x chunk, normalize, transpose, bf16 -> swizzled Hs --
  for (int p = 0; p < 4; ++p) {
    int c0 = p * 64;
#pragma unroll
    for (int i = 0; i < 4; ++i) {
      int crow = (tid >> 4) + i * 16;
      int c = c0 + crow;
      float4 v = *(const float4*)&xb[(size_t)c * NSP + n0 + (tid & 15) * 4];
      float a = aco[c], bb = bco[c];
      v.x = v.x * a + bb; v.y = v.y * a + bb;
      v.z = v.z * a + bb; v.w = v.w * a + bb;
      *(float4*)&Ts[crow][(tid & 15) * 4] = v;   // Ts[c_local][n_local]
    }
    __syncthreads();
    {
      int n = tid >> 2, seg = tid & 3;
#pragma unroll
      for (int u = 0; u < 2; ++u) {
        int cb = seg * 16 + u * 8;
        bf16x8 r;
#pragma unroll
        for (int j = 0; j < 8; ++j) r[j] = f2bf(Ts[cb + j][n]);
        int chunk = (c0 + cb) >> 3;
        *(bf16x8*)(Hs + n * 256 + ((chunk ^ (n & 7)) * 8)) = r;
      }
    }
    __syncthreads();
  }
  // ---- extract B-frags (rows = this wave's 16 n) ----
  int w = tid >> 6, lane = tid & 63, quad = lane >> 4, l16 = lane & 15;
  bf16x8 a_h[8];
  {
    int row = w * 16 + l16;
#pragma unroll
    for (int kc = 0; kc < 8; ++kc)
      a_h[kc] = *(bf16x8*)(Hs + row * 256 + (((kc * 4 + quad) ^ (row & 7)) * 8));
  }
  __syncthreads();  // all waves extracted; smem reusable as Fo
  // ---- 3 projections ----
  for (int op = 0; op < 3; ++op) {
    const short* wt = (op == 0) ? wqt : (op == 1) ? wkt : wvt;
    const float* bias = (op == 0) ? bq : (op == 1) ? bk : bv;
    f32x4 acc[16];
#pragma unroll
    for (int mb = 0; mb < 16; ++mb) acc[mb] = (f32x4){0.f, 0.f, 0.f, 0.f};
#pragma unroll 4
    for (int mb = 0; mb < 16; ++mb) {
      const short* wp = wt + (size_t)(mb * 16 + l16) * CCH + quad * 8;
#pragma unroll
      for (int kc = 0; kc < 8; ++kc) {
        bf16x8 af = *(const bf16x8*)(wp + kc * 32);
        acc[mb] = __builtin_amdgcn_mfma_f32_16x16x32_bf16(af, a_h[kc], acc[mb], 0, 0, 0);
      }
    }
    int n = n0 + w * 16 + l16;
    if (op == 2) {  // v: [c][n] direct scalar stores
      short* ob = vo + (size_t)b * CCH * NSP;
#pragma unroll
      for (int mb = 0; mb < 16; ++mb)
#pragma unroll
        for (int r = 0; r < 4; ++r) {
          int d = mb * 16 + quad * 4 + r;
          ob[(size_t)d * NSP + n] = f2bf(acc[mb][r] + bias[d]);
        }
    } else {  // q/k: transpose via Fo -> [n][c] b128 stores
      float sc = (op == 0) ? ATTN_SCALE : 1.f;
      int nl = w * 16 + l16;
#pragma unroll
      for (int mb = 0; mb < 16; ++mb)
#pragma unroll
        for (int r = 0; r < 4; ++r) {
          int d = mb * 16 + quad * 4 + r;
          Fo[nl * 264 + d] = f2bf((acc[mb][r] + bias[d]) * sc);
        }
      __syncthreads();
      short* ob = ((op == 0) ? qo : ko) + (size_t)b * NSP * CCH;
#pragma unroll
      for (int it = 0; it < 2; ++it) {
        int idx = tid + 256 * it;
        int row = idx >> 3, seg = idx & 7;
        short* dst = ob + (size_t)(n0 + row) * CCH + seg * 32;
#pragma unroll
        for (int i = 0; i < 4; ++i)
          *(bf16x8*)(dst + i * 8) = *(bf16x8*)(Fo + row * 264 + seg * 32 + i * 8);
      }
      __syncthreads();
    }
  }
}

// ------ flash attention: 8 waves, 16 q/wave, 128 q/block (round-5 shape) ----
// q,k: [b][n][c] bf16 (q pre-scaled); v: [b][c][n] bf16.
// Writes NORMALIZED partial O [kh][b][n][c] bf16 + m,l stats [kh][b][n].
__global__ __launch_bounds__(512, 1) void attn_kernel(
    const short* __restrict__ q, const short* __restrict__ k,
    const short* __restrict__ v, short* __restrict__ po,
    float* __restrict__ pm, float* __restrict__ pl) {
  __shared__ __align__(16) unsigned char smem[65536];   // 64 KB
  short* Ks = (short*)smem;            // [64 m][256 c] swizzled (also Q stage)
  short* Vs = (short*)(smem + 32768);  // [256 c][64 m] swizzled
  short* Fo = (short*)smem;            // epilogue [64 n][264 c] bf16

  int bx = blockIdx.x;
  int b = bx & 3;
  int n0 = ((bx >> 2) & 31) << 7;   // 128-query block
  int kh = bx >> 7;                 // key half
  const short* qb = q + (size_t)b * NSP * CCH;
  const short* kb = k + (size_t)b * NSP * CCH;
  const short* vb = v + (size_t)b * CCH * NSP;
  int tid = threadIdx.x;
  int w = tid >> 6, lane = tid & 63, quad = lane >> 4, l16 = lane & 15;

  // staging geometry (512 threads)
  int krow = tid >> 3, kch8 = tid & 7;   // K/Q: row krow, chunks kch8+8i
  int ksw = (kch8 ^ (krow & 7)) * 8;     // swizzled base (chunk+8i keeps row&7)
  int vrow = tid >> 1, vc = tid & 1;     // V: row vrow, chunks vc*4+i

  // ---- stage Q in 2 passes of 64 rows through Ks; extract B-frags ----
  bf16x8 a_q[8];
#pragma unroll
  for (int p = 0; p < 2; ++p) {
    const short* qp = qb + (size_t)(n0 + p * 64 + krow) * CCH + kch8 * 8;
#pragma unroll
    for (int i = 0; i < 4; ++i)
      *(bf16x8*)(Ks + krow * 256 + ksw + 64 * i) = *(const bf16x8*)(qp + 64 * i);
    __syncthreads();
    if ((w >> 2) == p) {
      int row = (w & 3) * 16 + l16;
#pragma unroll
      for (int kc = 0; kc < 8; ++kc)
        a_q[kc] = *(bf16x8*)(Ks + row * 256 + (((kc * 4 + quad) ^ (row & 7)) * 8));
    }
    __syncthreads();
  }

  int mbase = kh * TILES_PER_PART * 64;
  // ---- stage tile 0 ----
  {
    const short* kp = kb + (size_t)(mbase + krow) * CCH + kch8 * 8;
#pragma unroll
    for (int i = 0; i < 4; ++i)
      *(bf16x8*)(Ks + krow * 256 + ksw + 64 * i) = *(const bf16x8*)(kp + 64 * i);
    const short* vp = vb + (size_t)vrow * NSP + mbase;
#pragma unroll
    for (int i = 0; i < 4; ++i) {
      int c = vc * 4 + i;
      *(bf16x8*)(Vs + vrow * 64 + ((c ^ (vrow & 7)) * 8)) =
          *(const bf16x8*)(vp + c * 8);
    }
  }
  __syncthreads();

  f32x4 accO[16];  // O^T C-layout: ch = cb*16 + quad*4 + r, query = w*16+l16
#pragma unroll
  for (int cb = 0; cb < 16; ++cb) accO[cb] = (f32x4){0.f, 0.f, 0.f, 0.f};
  float m_run = -1e30f, l_run = 0.f;

#pragma unroll 1
  for (int t = 0; t < TILES_PER_PART; ++t) {
    // ---- prefetch next tile into registers (lands during compute) ----
    bf16x8 kr[4], vr[4];
    if (t < TILES_PER_PART - 1) {
      int m0 = mbase + (t + 1) * 64;
      const short* kp = kb + (size_t)(m0 + krow) * CCH + kch8 * 8;
#pragma unroll
      for (int i = 0; i < 4; ++i) kr[i] = *(const bf16x8*)(kp + 64 * i);
      const short* vp = vb + (size_t)vrow * NSP + m0;
#pragma unroll
      for (int i = 0; i < 4; ++i) vr[i] = *(const bf16x8*)(vp + (vc * 4 + i) * 8);
    }
    // ---- S^T = K Q^T : rows = 64 keys, cols = this wave's 16 queries ----
    f32x4 s[4];
#pragma unroll
    for (int mb = 0; mb < 4; ++mb) s[mb] = (f32x4){0.f, 0.f, 0.f, 0.f};
#pragma unroll
    for (int kc = 0; kc < 8; ++kc) {
#pragma unroll
      for (int mb = 0; mb < 4; ++mb) {
        int row = mb * 16 + l16;
        bf16x8 kf = *(bf16x8*)(Ks + row * 256 + (((kc * 4 + quad) ^ (row & 7)) * 8));
        s[mb] = __builtin_amdgcn_mfma_f32_16x16x32_bf16(kf, a_q[kc], s[mb], 0, 0, 0);
      }
    }
    // ---- online softmax: per-lane scalar stats (one query per lane) ----
    float mx = -1e30f;
#pragma unroll
    for (int mb = 0; mb < 4; ++mb)
#pragma unroll
      for (int r = 0; r < 4; ++r) mx = fmaxf(mx, s[mb][r]);
    mx = fmaxf(mx, __shfl_xor(mx, 16));
    mx = fmaxf(mx, __shfl_xor(mx, 32));
    float mnew = fmaxf(m_run, mx);
    float alpha = __expf(m_run - mnew);
    m_run = mnew;
    float ls = 0.f;
    bf16x4 pb[4];
#pragma unroll
    for (int mb = 0; mb < 4; ++mb)
#pragma unroll
      for (int r = 0; r < 4; ++r) {
        float p = __expf(s[mb][r] - mnew);
        ls += p;
        pb[mb][r] = f2bf(p);
      }
    ls += __shfl_xor(ls, 16);
    ls += __shfl_xor(ls, 32);
    l_run = l_run * alpha + ls;
#pragma unroll
    for (int cb = 0; cb < 16; ++cb) accO[cb] *= alpha;
    // ---- O^T += V P^T : A = V-frag (b64), B = pb from registers ----
#pragma unroll
    for (int kw = 0; kw < 4; ++kw) {
#pragma unroll
      for (int cb = 0; cb < 16; ++cb) {
        int row = cb * 16 + l16;
        int chunk = (kw * 2 + (quad >> 1)) ^ (row & 7);
        bf16x4 vf = *(bf16x4*)(Vs + row * 64 + chunk * 8 + (quad & 1) * 4);
        accO[cb] = mfma16x16x16(vf, pb[kw], accO[cb]);
      }
    }
    __syncthreads();
    if (t < TILES_PER_PART - 1) {
#pragma unroll
      for (int i = 0; i < 4; ++i)
        *(bf16x8*)(Ks + krow * 256 + ksw + 64 * i) = kr[i];
#pragma unroll
      for (int i = 0; i < 4; ++i) {
        int c = vc * 4 + i;
        *(bf16x8*)(Vs + vrow * 64 + ((c ^ (vrow & 7)) * 8)) = vr[i];
      }
      __syncthreads();
    }
  }
  // ---- stats ----
  size_t sbase = ((size_t)kh * BB + b) * NSP + n0;
  if (quad == 0) {
    pm[sbase + w * 16 + l16] = m_run;
    pl[sbase + w * 16 + l16] = l_run;
  }
  // ---- epilogue: normalized bf16 O -> po [kh][b][n][c], LDS transpose ----
  float linv = 1.f / l_run;
  short* ob = po + ((size_t)kh * BB + b) * NSP * CCH;
#pragma unroll
  for (int p = 0; p < 2; ++p) {
    __syncthreads();
    if ((w >> 2) == p) {
      int nloc = (w & 3) * 16 + l16;
#pragma unroll
      for (int cb = 0; cb < 16; ++cb)
#pragma unroll
        for (int r = 0; r < 4; ++r)
          Fo[nloc * 264 + cb * 16 + quad * 4 + r] = f2bf(accO[cb][r] * linv);
    }
    __syncthreads();
    int row = tid >> 3, seg = tid & 7;
    short* dst = ob + (size_t)(n0 + p * 64 + row) * CCH + seg * 32;
#pragma unroll
    for (int i = 0; i < 4; ++i)
      *(bf16x8*)(dst + i * 8) = *(bf16x8*)(Fo + row * 264 + seg * 32 + i * 8);
  }
}

// ------- proj: frag-direct MFMA, 2-way merge in registers, +bias+resid ------
__global__ __launch_bounds__(256) void proj_kernel(
    const short* __restrict__ po, const float* __restrict__ pm,
    const float* __restrict__ pl, const short* __restrict__ wpt,
    const float* __restrict__ bp, const float* __restrict__ x,
    float* __restrict__ out) {
  int n0 = blockIdx.x * 64;
  int dh = blockIdx.y * 128;
  int b = blockIdx.z;
  int tid = threadIdx.x;
  int w = tid >> 6, lane = tid & 63, quad = lane >> 4, l16 = lane & 15;
  int n = n0 + w * 16 + l16;

  float wgt[KSPLIT];
  {
    float m0 = pm[(size_t)b * NSP + n];
    float m1 = pm[((size_t)BB + b) * NSP + n];
    float l0 = pl[(size_t)b * NSP + n];
    float l1 = pl[((size_t)BB + b) * NSP + n];
    float M = fmaxf(m0, m1);
    float w0 = __expf(m0 - M) * l0, w1 = __expf(m1 - M) * l1;
    float linv = 1.f / (w0 + w1);
    wgt[0] = w0 * linv;
    wgt[1] = w1 * linv;
  }

  f32x4 acc[8];
#pragma unroll
  for (int mb = 0; mb < 8; ++mb) acc[mb] = (f32x4){0.f, 0.f, 0.f, 0.f};

  const short* pob = po + ((size_t)b * NSP + n) * CCH;
#pragma unroll 2
  for (int kc = 0; kc < 8; ++kc) {
    int coff = kc * 32 + quad * 8;
    bf16x8 f0 = *(const bf16x8*)(pob + coff);
    bf16x8 f1 = *(const bf16x8*)(pob + (size_t)BB * NSP * CCH + coff);
    bf16x8 bm;
#pragma unroll
    for (int e = 0; e < 8; ++e)
      bm[e] = f2bf(wgt[0] * bf2f(f0[e]) + wgt[1] * bf2f(f1[e]));
#pragma unroll
    for (int mb = 0; mb < 8; ++mb) {
      bf16x8 af = *(const bf16x8*)(wpt + (size_t)(dh + mb * 16 + l16) * CCH + coff);
      acc[mb] = __builtin_amdgcn_mfma_f32_16x16x32_bf16(af, bm, acc[mb], 0, 0, 0);
    }
  }
#pragma unroll
  for (int mb = 0; mb < 8; ++mb) {
#pragma unroll
    for (int r = 0; r < 4; ++r) {
      int d = dh + mb * 16 + quad * 4 + r;
      size_t off = ((size_t)b * CCH + d) * NSP + n;
      out[off] = (acc[mb][r] + bp[d] + x[off]) * RSQRT2;
    }
  }
}

extern "C" void kernel_launch(void* const* d_in, const int* in_sizes, int n_in,
                              void* d_out, int out_size, void* d_ws, size_t ws_size,
                              hipStream_t stream) {
  const float* x  = (const float*)d_in[0];
  const float* gw = (const float*)d_in[1];
  const float* gb = (const float*)d_in[2];
  const float* Wq = (const float*)d_in[3];
  const float* bq = (const float*)d_in[4];
  const float* Wk = (const float*)d_in[5];
  const float* bk = (const float*)d_in[6];
  const float* Wv = (const float*)d_in[7];
  const float* bv = (const float*)d_in[8];
  const float* Wp = (const float*)d_in[9];
  const float* bp = (const float*)d_in[10];
  float* out = (float*)d_out;

  const size_t SZ = (size_t)BB * CCH * NSP;  // 4.19M elems
  short* qb  = (short*)d_ws;                 // bf16 [b][n][c], pre-scaled
  short* kb  = qb + SZ;                      // bf16 [b][n][c]
  short* vb  = kb + SZ;                      // bf16 [b][c][n]
  short* poT = vb + SZ;                      // bf16 [2][b][n][c] normalized
  float* pm  = (float*)(poT + (size_t)KSPLIT * SZ);  // [2][b][n]
  float* pl  = pm + (size_t)KSPLIT * BB * NSP;
  float* stats = pl + (size_t)KSPLIT * BB * NSP;     // [b][32][2]
  short* wts = (short*)(stats + BB * 64);            // bf16 [4][256][256]
  short* wqt = wts;
  short* wkt = wts + (size_t)CCH * CCH;
  short* wvt = wts + (size_t)2 * CCH * CCH;
  short* wpt = wts + (size_t)3 * CCH * CCH;

  gn_stats<<<dim3(BB * 32), dim3(256), 0, stream>>>(x, stats);
  prep_w<<<dim3(4, 4, 4), dim3(256), 0, stream>>>(Wq, Wk, Wv, Wp, wts);
  qkvg_kernel<<<dim3(256), dim3(256), 0, stream>>>(
      x, stats, gw, gb, wqt, wkt, wvt, bq, bk, bv, qb, kb, vb);
  attn_kernel<<<dim3(256), dim3(512), 0, stream>>>(qb, kb, vb, poT, pm, pl);
  proj_kernel<<<dim3(64, 2, BB), dim3(256), 0, stream>>>(
      poT, pm, pl, wpt, bp, x, out);
}